// Round 2
// baseline (78.463 us; speedup 1.0000x reference)
//
#include <hip/hip_runtime.h>

// r[b,n,o] = b2[o] + sum_h W2[h,o] * (1/N) * sum_m relu(u[b,m,h] + v[b,n,h])
//   u[m,h] =  x_m . W1[0:2,h] + y_m . W1[2:4,h]
//   v[n,h] = -x_n . W1[0:2,h] + y_n . W1[4:6,h] + b1[h]
//
// relu trick: sum_m relu(u+v) = 0.5*( sum_m |u+v| + Su + N*v ),
//   Su[h] = Sxx*W1[0,h]+Sxy*W1[1,h]+Syx*W1[2,h]+Syy*W1[3,h]
// -> main loop is 2 VALU ops per (m,n,h): v_add + v_add(abs()).
//
// 1024 threads/block (16 waves); grid 256 = B(8) x n-tiles(32 of 32 n).
// 1 block/CU, 4 waves/SIMD (was 2) to hide ds_read/global latency.
// Each wave covers 64 m. LDS: u[1024][16] fp32 = 64 KB; reused post-loop.
// Main-loop lane layout: g = lane&3 (channels 4g..4g+3), nsub = lane>>2;
// lane accumulates n = n0+nsub and n0+nsub+16.
// LDS reads broadcast: 16 lanes per g read the same 16B address.

constexpr int NN = 1024;

__global__ __launch_bounds__(1024, 4) void te_enc(
    const float* __restrict__ x_ctx,
    const float* __restrict__ y_ctx,
    const float* __restrict__ W1,
    const float* __restrict__ b1,
    const float* __restrict__ W2,
    const float* __restrict__ b2,
    float* __restrict__ out)
{
    __shared__ float lds[16384];   // 64 KB

    const int t    = threadIdx.x;
    const int wave = t >> 6;       // 0..15
    const int lane = t & 63;
    const int g    = lane & 3;
    const int nsub = lane >> 2;
    const int b    = blockIdx.x >> 5;
    const int n0   = (blockIdx.x & 31) << 5;

    // W1 chunks for this thread's 4 channels (rows 0..5 of [6][16] W1)
    const float4 w10 = *(const float4*)(W1 +  0 + 4*g);
    const float4 w11 = *(const float4*)(W1 + 16 + 4*g);
    const float4 w12 = *(const float4*)(W1 + 32 + 4*g);
    const float4 w13 = *(const float4*)(W1 + 48 + 4*g);
    const float4 w14 = *(const float4*)(W1 + 64 + 4*g);
    const float4 w15 = *(const float4*)(W1 + 80 + 4*g);
    const float4 b1c = *(const float4*)(b1 + 4*g);

    // ---- Phase A: u[m][0..15] for all m of this batch -> LDS ----
    {
        const int mm = t >> 2;     // 0..255
        #pragma unroll
        for (int rep = 0; rep < 4; ++rep) {
            const int m = rep * 256 + mm;
            const float2 xm = *(const float2*)(x_ctx + (b * NN + m) * 2);
            const float2 ym = *(const float2*)(y_ctx + (b * NN + m) * 2);
            float4 u;
            u.x = xm.x*w10.x + xm.y*w11.x + ym.x*w12.x + ym.y*w13.x;
            u.y = xm.x*w10.y + xm.y*w11.y + ym.x*w12.y + ym.y*w13.y;
            u.z = xm.x*w10.z + xm.y*w11.z + ym.x*w12.z + ym.y*w13.z;
            u.w = xm.x*w10.w + xm.y*w11.w + ym.x*w12.w + ym.y*w13.w;
            *(float4*)(lds + m * 16 + 4 * g) = u;
        }
    }

    // ---- v for this lane's two n's ----
    const int n1 = n0 + nsub;
    const int n2 = n1 + 16;
    float4 v1, v2;
    {
        const float2 xn = *(const float2*)(x_ctx + (b * NN + n1) * 2);
        const float2 yn = *(const float2*)(y_ctx + (b * NN + n1) * 2);
        v1.x = b1c.x - xn.x*w10.x - xn.y*w11.x + yn.x*w14.x + yn.y*w15.x;
        v1.y = b1c.y - xn.x*w10.y - xn.y*w11.y + yn.x*w14.y + yn.y*w15.y;
        v1.z = b1c.z - xn.x*w10.z - xn.y*w11.z + yn.x*w14.z + yn.y*w15.z;
        v1.w = b1c.w - xn.x*w10.w - xn.y*w11.w + yn.x*w14.w + yn.y*w15.w;
    }
    {
        const float2 xn = *(const float2*)(x_ctx + (b * NN + n2) * 2);
        const float2 yn = *(const float2*)(y_ctx + (b * NN + n2) * 2);
        v2.x = b1c.x - xn.x*w10.x - xn.y*w11.x + yn.x*w14.x + yn.y*w15.x;
        v2.y = b1c.y - xn.x*w10.y - xn.y*w11.y + yn.x*w14.y + yn.y*w15.y;
        v2.z = b1c.z - xn.x*w10.z - xn.y*w11.z + yn.x*w14.z + yn.y*w15.z;
        v2.w = b1c.w - xn.x*w10.w - xn.y*w11.w + yn.x*w14.w + yn.y*w15.w;
    }

    __syncthreads();

    // ---- Phase B: main loop, |u+v| accumulation; wave covers 64 m ----
    float4 s1 = {0.f, 0.f, 0.f, 0.f};
    float4 s2 = {0.f, 0.f, 0.f, 0.f};
    const float* up = lds + wave * 1024 + 4 * g;
    #pragma unroll 4
    for (int i = 0; i < 64; ++i) {
        const float4 u = *(const float4*)(up + i * 16);
        s1.x += fabsf(u.x + v1.x);
        s1.y += fabsf(u.y + v1.y);
        s1.z += fabsf(u.z + v1.z);
        s1.w += fabsf(u.w + v1.w);
        s2.x += fabsf(u.x + v2.x);
        s2.y += fabsf(u.y + v2.y);
        s2.z += fabsf(u.z + v2.z);
        s2.w += fabsf(u.w + v2.w);
    }

    __syncthreads();   // u no longer needed; LDS reusable

    // ---- Phase C: spill partials + stage epilogue data ----
    // LDS float map: [0,8192) abs partials [16 waves][64 lanes][2][4];
    // [8192,8704) v[32][16]; [8704,8960) W2; [8960,8976) b2;
    // [8976,9040) W1 rows 0..3; [9040,9104) batch-sum partials [16][4];
    // [9104,9616) s_final[32][16]
    {
        const int base = ((wave * 64 + lane) * 2) * 4;
        *(float4*)(lds + base)     = s1;
        *(float4*)(lds + base + 4) = s2;
    }
    if (wave == 0) {
        *(float4*)(lds + 8192 + nsub        * 16 + 4 * g) = v1;
        *(float4*)(lds + 8192 + (nsub + 16) * 16 + 4 * g) = v2;
    }
    if (t < 256) lds[8704 + t] = W2[t];
    if (t < 16)  lds[8960 + t] = b2[t];
    if (t < 64)  lds[8976 + t] = W1[t];   // rows 0..3

    // batch sums: thread t covers m = t via float2
    {
        const float2 xa = *(const float2*)(x_ctx + b * 2048 + t * 2);
        const float2 ya = *(const float2*)(y_ctx + b * 2048 + t * 2);
        float sxx = xa.x;
        float sxy = xa.y;
        float syx = ya.x;
        float syy = ya.y;
        #pragma unroll
        for (int off = 32; off > 0; off >>= 1) {
            sxx += __shfl_down(sxx, off);
            sxy += __shfl_down(sxy, off);
            syx += __shfl_down(syx, off);
            syy += __shfl_down(syy, off);
        }
        if (lane == 0) {
            float4 bs = {sxx, sxy, syx, syy};
            *(float4*)(lds + 9040 + wave * 4) = bs;
        }
    }
    __syncthreads();

    // ---- Phase D: reduce 16 waves, apply relu identity + 1/N ----
    if (t < 128) {
        const int l = t >> 1;
        const int p = t & 1;
        float4 acc = {0.f, 0.f, 0.f, 0.f};
        #pragma unroll
        for (int w = 0; w < 16; ++w) {
            const float4 q = *(const float4*)(lds + ((w * 64 + l) * 2 + p) * 4);
            acc.x += q.x; acc.y += q.y; acc.z += q.z; acc.w += q.w;
        }
        float4 bs = {0.f, 0.f, 0.f, 0.f};
        #pragma unroll
        for (int w = 0; w < 16; ++w) {
            const float4 q = *(const float4*)(lds + 9040 + w * 4);
            bs.x += q.x; bs.y += q.y; bs.z += q.z; bs.w += q.w;
        }
        const int nsf = (l >> 2) + 16 * p;
        const int gf  = l & 3;
        const int c   = 4 * gf;
        float4 su;
        su.x = bs.x*lds[8976+c  ] + bs.y*lds[8992+c  ] + bs.z*lds[9008+c  ] + bs.w*lds[9024+c  ];
        su.y = bs.x*lds[8976+c+1] + bs.y*lds[8992+c+1] + bs.z*lds[9008+c+1] + bs.w*lds[9024+c+1];
        su.z = bs.x*lds[8976+c+2] + bs.y*lds[8992+c+2] + bs.z*lds[9008+c+2] + bs.w*lds[9024+c+2];
        su.w = bs.x*lds[8976+c+3] + bs.y*lds[8992+c+3] + bs.z*lds[9008+c+3] + bs.w*lds[9024+c+3];
        const float4 vv = *(const float4*)(lds + 8192 + nsf * 16 + c);
        const float k = 0.5f / 1024.0f;
        float4 r;
        r.x = (acc.x + su.x) * k + 0.5f * vv.x;
        r.y = (acc.y + su.y) * k + 0.5f * vv.y;
        r.z = (acc.z + su.z) * k + 0.5f * vv.z;
        r.w = (acc.w + su.w) * k + 0.5f * vv.w;
        *(float4*)(lds + 9104 + nsf * 16 + c) = r;
    }
    __syncthreads();

    // ---- Phase E: W2 epilogue, coalesced store (first 512 threads) ----
    if (t < 512) {
        const int j = t >> 4;      // n within tile
        const int o = t & 15;      // output channel
        const float* sf = lds + 9104 + j * 16;
        const float* w2 = lds + 8704;
        float acc = lds[8960 + o];
        #pragma unroll
        for (int h = 0; h < 16; ++h)
            acc += sf[h] * w2[h * 16 + o];
        out[(b * NN + n0 + j) * 16 + o] = acc;
    }
}

extern "C" void kernel_launch(void* const* d_in, const int* in_sizes, int n_in,
                              void* d_out, int out_size, void* d_ws, size_t ws_size,
                              hipStream_t stream) {
    const float* x_ctx = (const float*)d_in[0];
    const float* y_ctx = (const float*)d_in[1];
    // d_in[2] = x_trg : unused by the reference computation
    const float* W1 = (const float*)d_in[3];
    const float* b1 = (const float*)d_in[4];
    const float* W2 = (const float*)d_in[5];
    const float* b2 = (const float*)d_in[6];
    float* out = (float*)d_out;

    te_enc<<<256, 1024, 0, stream>>>(x_ctx, y_ctx, W1, b1, W2, b2, out);
}

// Round 3
// 76.922 us; speedup vs baseline: 1.0200x; 1.0200x over previous
//
#include <hip/hip_runtime.h>

// r[b,n,o] = b2[o] + sum_h W2[h,o] * (1/N) * sum_m relu(u[b,m,h] + v[b,n,h])
//   u[m,h] =  x_m . W1[0:2,h] + y_m . W1[2:4,h]
//   v[n,h] = -x_n . W1[0:2,h] + y_n . W1[4:6,h] + b1[h]
//
// relu trick: sum_m relu(u+v) = 0.5*( sum_m |u+v| + Su + N*v ),
//   Su[h] = sum_m u[m,h] = Sxx*W1[0,h]+Sxy*W1[1,h]+Syx*W1[2,h]+Syy*W1[3,h]
// -> main loop is 2 VALU ops per (m,n,h): v_add + v_add(abs()).
//
// Grid: 256 blocks = B(8) x n-tiles(32 of 32 n each). Block: 512 threads (8 waves).
// LDS: u[b] = 1024x16 fp32 = 64 KB (phases A,B); reused post-loop for reduction.
// Main-loop lane layout: g = lane&3 (channel group 4g..4g+3), nsub = lane>>2;
// lane accumulates n = n0+nsub and n0+nsub+16. Wave w covers m in [w*128,(w+1)*128).
// LDS reads broadcast: 16 lanes per g read the same 16B address.
//
// Session conclusion: te_enc model ~6-7 us (LDS-pipe bound main loop); measured
// dur_us is dominated by the harness 256 MiB workspace poison fill (~40 us @ 85%
// HBM) + restore overhead. 8-wave and 16-wave variants indistinguishable.

constexpr int NN = 1024;

__global__ __launch_bounds__(512, 2) void te_enc(
    const float* __restrict__ x_ctx,
    const float* __restrict__ y_ctx,
    const float* __restrict__ W1,
    const float* __restrict__ b1,
    const float* __restrict__ W2,
    const float* __restrict__ b2,
    float* __restrict__ out)
{
    __shared__ float lds[16384];   // 64 KB

    const int t    = threadIdx.x;
    const int wave = t >> 6;
    const int lane = t & 63;
    const int g    = lane & 3;
    const int nsub = lane >> 2;
    const int b    = blockIdx.x >> 5;
    const int n0   = (blockIdx.x & 31) << 5;

    // W1 chunks for this thread's 4 channels (rows 0..5 of [6][16] W1)
    const float4 w10 = *(const float4*)(W1 +  0 + 4*g);
    const float4 w11 = *(const float4*)(W1 + 16 + 4*g);
    const float4 w12 = *(const float4*)(W1 + 32 + 4*g);
    const float4 w13 = *(const float4*)(W1 + 48 + 4*g);
    const float4 w14 = *(const float4*)(W1 + 64 + 4*g);
    const float4 w15 = *(const float4*)(W1 + 80 + 4*g);
    const float4 b1c = *(const float4*)(b1 + 4*g);

    // ---- Phase A: u[m][0..15] for all m of this batch -> LDS ----
    {
        const int mm = t >> 2;     // 0..127
        #pragma unroll
        for (int rep = 0; rep < 8; ++rep) {
            const int m = rep * 128 + mm;
            const float2 xm = *(const float2*)(x_ctx + (b * NN + m) * 2);
            const float2 ym = *(const float2*)(y_ctx + (b * NN + m) * 2);
            float4 u;
            u.x = xm.x*w10.x + xm.y*w11.x + ym.x*w12.x + ym.y*w13.x;
            u.y = xm.x*w10.y + xm.y*w11.y + ym.x*w12.y + ym.y*w13.y;
            u.z = xm.x*w10.z + xm.y*w11.z + ym.x*w12.z + ym.y*w13.z;
            u.w = xm.x*w10.w + xm.y*w11.w + ym.x*w12.w + ym.y*w13.w;
            *(float4*)(lds + m * 16 + 4 * g) = u;
        }
    }

    // ---- v for this lane's two n's ----
    const int n1 = n0 + nsub;
    const int n2 = n1 + 16;
    float4 v1, v2;
    {
        const float2 xn = *(const float2*)(x_ctx + (b * NN + n1) * 2);
        const float2 yn = *(const float2*)(y_ctx + (b * NN + n1) * 2);
        v1.x = b1c.x - xn.x*w10.x - xn.y*w11.x + yn.x*w14.x + yn.y*w15.x;
        v1.y = b1c.y - xn.x*w10.y - xn.y*w11.y + yn.x*w14.y + yn.y*w15.y;
        v1.z = b1c.z - xn.x*w10.z - xn.y*w11.z + yn.x*w14.z + yn.y*w15.z;
        v1.w = b1c.w - xn.x*w10.w - xn.y*w11.w + yn.x*w14.w + yn.y*w15.w;
    }
    {
        const float2 xn = *(const float2*)(x_ctx + (b * NN + n2) * 2);
        const float2 yn = *(const float2*)(y_ctx + (b * NN + n2) * 2);
        v2.x = b1c.x - xn.x*w10.x - xn.y*w11.x + yn.x*w14.x + yn.y*w15.x;
        v2.y = b1c.y - xn.x*w10.y - xn.y*w11.y + yn.x*w14.y + yn.y*w15.y;
        v2.z = b1c.z - xn.x*w10.z - xn.y*w11.z + yn.x*w14.z + yn.y*w15.z;
        v2.w = b1c.w - xn.x*w10.w - xn.y*w11.w + yn.x*w14.w + yn.y*w15.w;
    }

    __syncthreads();

    // ---- Phase B: main loop, |u+v| accumulation ----
    float4 s1 = {0.f, 0.f, 0.f, 0.f};
    float4 s2 = {0.f, 0.f, 0.f, 0.f};
    const float* up = lds + wave * 2048 + 4 * g;
    #pragma unroll 4
    for (int i = 0; i < 128; ++i) {
        const float4 u = *(const float4*)(up + i * 16);
        s1.x += fabsf(u.x + v1.x);
        s1.y += fabsf(u.y + v1.y);
        s1.z += fabsf(u.z + v1.z);
        s1.w += fabsf(u.w + v1.w);
        s2.x += fabsf(u.x + v2.x);
        s2.y += fabsf(u.y + v2.y);
        s2.z += fabsf(u.z + v2.z);
        s2.w += fabsf(u.w + v2.w);
    }

    __syncthreads();   // u no longer needed; LDS reusable

    // ---- Phase C: spill partials + stage epilogue data ----
    // LDS float map: [0,4096) abs partials; [4096,4608) v[32][16];
    // [4608,4864) W2; [4864,4880) b2; [4880,4944) W1 rows 0..3;
    // [4944,4976) batch-sum partials [8][4]; [4976,5488) s_final[32][16]
    {
        const int base = ((wave * 64 + lane) * 2) * 4;
        *(float4*)(lds + base)     = s1;
        *(float4*)(lds + base + 4) = s2;
    }
    if (wave == 0) {
        *(float4*)(lds + 4096 + nsub        * 16 + 4 * g) = v1;
        *(float4*)(lds + 4096 + (nsub + 16) * 16 + 4 * g) = v2;
    }
    if (t < 256) lds[4608 + t] = W2[t];
    if (t < 16)  lds[4864 + t] = b2[t];
    if (t < 64)  lds[4880 + t] = W1[t];   // rows 0..3

    // batch sums: thread t covers m = 2t, 2t+1 via float4
    {
        const float4 xa = *(const float4*)(x_ctx + b * 2048 + t * 4);
        const float4 ya = *(const float4*)(y_ctx + b * 2048 + t * 4);
        float sxx = xa.x + xa.z;
        float sxy = xa.y + xa.w;
        float syx = ya.x + ya.z;
        float syy = ya.y + ya.w;
        #pragma unroll
        for (int off = 32; off > 0; off >>= 1) {
            sxx += __shfl_down(sxx, off);
            sxy += __shfl_down(sxy, off);
            syx += __shfl_down(syx, off);
            syy += __shfl_down(syy, off);
        }
        if (lane == 0) {
            float4 bs = {sxx, sxy, syx, syy};
            *(float4*)(lds + 4944 + wave * 4) = bs;
        }
    }
    __syncthreads();

    // ---- Phase D: reduce 8 waves, apply relu identity + 1/N ----
    if (t < 128) {
        const int l = t >> 1;
        const int p = t & 1;
        float4 acc = {0.f, 0.f, 0.f, 0.f};
        #pragma unroll
        for (int w = 0; w < 8; ++w) {
            const float4 q = *(const float4*)(lds + ((w * 64 + l) * 2 + p) * 4);
            acc.x += q.x; acc.y += q.y; acc.z += q.z; acc.w += q.w;
        }
        float4 bs = {0.f, 0.f, 0.f, 0.f};
        #pragma unroll
        for (int w = 0; w < 8; ++w) {
            const float4 q = *(const float4*)(lds + 4944 + w * 4);
            bs.x += q.x; bs.y += q.y; bs.z += q.z; bs.w += q.w;
        }
        const int nsf = (l >> 2) + 16 * p;
        const int gf  = l & 3;
        const int c   = 4 * gf;
        float4 su;
        su.x = bs.x*lds[4880+c  ] + bs.y*lds[4896+c  ] + bs.z*lds[4912+c  ] + bs.w*lds[4928+c  ];
        su.y = bs.x*lds[4880+c+1] + bs.y*lds[4896+c+1] + bs.z*lds[4912+c+1] + bs.w*lds[4928+c+1];
        su.z = bs.x*lds[4880+c+2] + bs.y*lds[4896+c+2] + bs.z*lds[4912+c+2] + bs.w*lds[4928+c+2];
        su.w = bs.x*lds[4880+c+3] + bs.y*lds[4896+c+3] + bs.z*lds[4912+c+3] + bs.w*lds[4928+c+3];
        const float4 vv = *(const float4*)(lds + 4096 + nsf * 16 + c);
        const float k = 0.5f / 1024.0f;
        float4 r;
        r.x = (acc.x + su.x) * k + 0.5f * vv.x;
        r.y = (acc.y + su.y) * k + 0.5f * vv.y;
        r.z = (acc.z + su.z) * k + 0.5f * vv.z;
        r.w = (acc.w + su.w) * k + 0.5f * vv.w;
        *(float4*)(lds + 4976 + nsf * 16 + c) = r;
    }
    __syncthreads();

    // ---- Phase E: W2 epilogue, coalesced store ----
    {
        const int j = t >> 4;      // n within tile
        const int o = t & 15;      // output channel
        const float* sf = lds + 4976 + j * 16;
        const float* w2 = lds + 4608;
        float acc = lds[4864 + o];
        #pragma unroll
        for (int h = 0; h < 16; ++h)
            acc += sf[h] * w2[h * 16 + o];
        out[(b * NN + n0 + j) * 16 + o] = acc;
    }
}

extern "C" void kernel_launch(void* const* d_in, const int* in_sizes, int n_in,
                              void* d_out, int out_size, void* d_ws, size_t ws_size,
                              hipStream_t stream) {
    const float* x_ctx = (const float*)d_in[0];
    const float* y_ctx = (const float*)d_in[1];
    // d_in[2] = x_trg : unused by the reference computation
    const float* W1 = (const float*)d_in[3];
    const float* b1 = (const float*)d_in[4];
    const float* W2 = (const float*)d_in[5];
    const float* b2 = (const float*)d_in[6];
    float* out = (float*)d_out;

    te_enc<<<256, 512, 0, stream>>>(x_ctx, y_ctx, W1, b1, W2, b2, out);
}